// Round 17
// baseline (2688.410 us; speedup 1.0000x reference)
//
#include <hip/hip_runtime.h>

#define B_   256
#define T_   512
#define IN_  34
#define H_   80
#define L_   10
#define NC_  5
#define G4   320
#define TPB  640        // waves 0-4: serial chain (h-side); waves 5-9: xp producers (x-side)
#define HPS  96         // hist row: 4 slices x 24 f16 (20 used + 4 pad) = 48B-aligned slices
#define LAG  2          // producer lead (timesteps)

typedef _Float16 h2 __attribute__((ext_vector_type(2)));

template <int CTRL>
__device__ __forceinline__ float dpp_mov(float v) {
    return __int_as_float(__builtin_amdgcn_update_dpp(0, __float_as_int(v), CTRL, 0xF, 0xF, true));
}
__device__ __forceinline__ h2 bc(unsigned u) { return __builtin_bit_cast(h2, u); }
__device__ __forceinline__ h2 pkfma(h2 a, h2 b, h2 c) { return __builtin_elementwise_fma(a, b, c); }

// Weight layouts identical to R14 (proven): lane = e*4 + q4 owns, for all 4 gates,
// K-slice [20*q4, 20*q4+20) (x-side w1, h-side w2) of row gate*80+e.
__global__ void prep_kernel(const float* __restrict__ Wih0, const float* __restrict__ WihR,
                            const float* __restrict__ Whh,  const float* __restrict__ bih,
                            const float* __restrict__ bhh,
                            unsigned* __restrict__ w1, unsigned* __restrict__ w2,
                            float* __restrict__ bbuf) {
    int idx = blockIdx.x * 256 + threadIdx.x;          // dword index
    const int ND = L_ * 10 * G4 * 4;                   // 128000 dwords per half
    if (idx < ND) {
        int c    = idx & 3;
        int lane = (idx >> 2) % G4;
        int n    = ((idx >> 2) / G4) % 10;
        int l    = (idx >> 2) / (G4 * 10);
        int j = n * 4 + c;
        int gate = j / 10, q = j % 10;
        int e = lane >> 2, q4 = lane & 3;
        int row = gate * H_ + e;
        int k0 = 20 * q4 + 2 * q;
        float a, b;
        if (l == 0) {
            a = (k0     < IN_) ? Wih0[row * IN_ + k0]     : 0.f;
            b = (k0 + 1 < IN_) ? Wih0[row * IN_ + k0 + 1] : 0.f;
        } else {
            const float* p = WihR + ((size_t)(l - 1) * G4 + row) * H_;
            a = p[k0]; b = p[k0 + 1];
        }
        h2 pa; pa[0] = (_Float16)a; pa[1] = (_Float16)b;
        w1[idx] = __builtin_bit_cast(unsigned, pa);
        const float* ph = Whh + ((size_t)l * G4 + row) * H_;
        h2 pb; pb[0] = (_Float16)ph[k0]; pb[1] = (_Float16)ph[k0 + 1];
        w2[idx] = __builtin_bit_cast(unsigned, pb);
    }
    if (idx < L_ * G4) bbuf[idx] = bih[idx] + bhh[idx];
}

__global__ __launch_bounds__(TPB, 1) void lstm_stack_kernel(
    const float* __restrict__ x,      // [B,T,34]
    const uint4* __restrict__ w1,     // x-side weights (producers)
    const uint4* __restrict__ w2,     // h-side weights (chain)
    const float* __restrict__ bbuf,   // [10][320]
    const float* __restrict__ fcw,    // [5,80]
    const float* __restrict__ fcb,    // [5]
    float* __restrict__ out)          // [B,5]
{
    const int b    = blockIdx.x;
    const int tid  = threadIdx.x;             // 0..639
    const bool isProd = tid >= G4;            // waves 5-9 produce xp
    const int lane = isProd ? tid - G4 : tid; // 0..319
    const int e    = lane >> 2;               // h element 0..79
    const int q4   = lane & 3;                // K-slice id == final gate id (0=i 1=f 2=g 3=o)
    const int eS   = (e / 20) * 24 + (e % 20);  // sliced column for element e

    // chain waves get scheduler priority: their serial path gates every step
    if (!isProd) __builtin_amdgcn_s_setprio(1);

    const float mA  = (q4 == 2) ? -2.885390082f : -1.442695041f;
    const float bA  = (q4 == 2) ? 2.f : 1.f;
    const float cA0 = (q4 == 2) ? -1.f : 0.f;
    const bool  sel1 = (q4 & 1) != 0;
    const bool  sel2 = (q4 & 2) != 0;

    h2 ones; ones[0] = (_Float16)1.f; ones[1] = (_Float16)1.f;

    __shared__ __align__(16) _Float16 hist[T_][HPS];  // 96 KB: x (f16) then h history, sliced rows
    __shared__ __align__(16) float xp[4][4][84];      // 5.4 KB ring: [slot][gate][e]
    __shared__ __align__(16) _Float16 hs[2][4][24];   // h(t-1) ping-pong, sliced

    // ---- stage x -> f16 hist (zero-pad 34..79); slice pads never read ----
    for (int j = tid; j < T_ * H_; j += TPB) {
        int t = j / H_, k = j % H_;
        float v = (k < IN_) ? x[((size_t)b * T_ + t) * IN_ + k] : 0.f;
        hist[t][(k / 20) * 24 + (k % 20)] = (_Float16)v;
    }

    for (int l = 0; l < L_; ++l) {
        // ---- this lane's 40-dword weight half (proven-resident size) ----
        const uint4* wp = (isProd ? w1 : w2) + (size_t)l * 10 * G4 + lane;
        uint4 W0 = wp[0 * G4], W1 = wp[1 * G4], W2 = wp[2 * G4], W3 = wp[3 * G4], W4 = wp[4 * G4];
        uint4 W5 = wp[5 * G4], W6 = wp[6 * G4], W7 = wp[7 * G4], W8 = wp[8 * G4], W9 = wp[9 * G4];
        const float bias = isProd ? bbuf[l * G4 + q4 * H_ + e] : 0.f;

        if (tid < 96) ((unsigned*)hs)[tid] = 0;   // h(-1) = 0 (both buffers)
        __syncthreads();

        float cold = 0.f;
        int par = 0;

// 3 aligned LDS loads + per gate {1 pk_mul + 8 pk_fma_f16 (two 5-product chains) +
// 1 pk_add + 1 exact fdot2 promote} + 4-lane distribute-reduce:
// lane q4 ends with the 4-slice total of gate q4 in S.
#define DOTS_REDUCE(SLICEBASE)                                                       \
    const uint4* vba_ = (const uint4*)(SLICEBASE);                                   \
    uint4 LA_ = vba_[0], LB_ = vba_[1];                                              \
    uint2 LC_ = *(const uint2*)((const char*)(SLICEBASE) + 32);                      \
    h2 p0 = bc(LA_.x), p1 = bc(LA_.y), p2 = bc(LA_.z), p3 = bc(LA_.w);               \
    h2 p4 = bc(LB_.x), p5 = bc(LB_.y), p6 = bc(LB_.z), p7 = bc(LB_.w);               \
    h2 p8 = bc(LC_.x), p9 = bc(LC_.y);                                               \
    h2 i0 = bc(W0.x) * p0,            i1 = bc(W0.y) * p1;                            \
    i0 = pkfma(bc(W0.z), p2, i0);     i1 = pkfma(bc(W0.w), p3, i1);                  \
    i0 = pkfma(bc(W1.x), p4, i0);     i1 = pkfma(bc(W1.y), p5, i1);                  \
    i0 = pkfma(bc(W1.z), p6, i0);     i1 = pkfma(bc(W1.w), p7, i1);                  \
    i0 = pkfma(bc(W2.x), p8, i0);     i1 = pkfma(bc(W2.y), p9, i1);                  \
    h2 f0 = bc(W2.z) * p0,            f1 = bc(W2.w) * p1;                            \
    f0 = pkfma(bc(W3.x), p2, f0);     f1 = pkfma(bc(W3.y), p3, f1);                  \
    f0 = pkfma(bc(W3.z), p4, f0);     f1 = pkfma(bc(W3.w), p5, f1);                  \
    f0 = pkfma(bc(W4.x), p6, f0);     f1 = pkfma(bc(W4.y), p7, f1);                  \
    f0 = pkfma(bc(W4.z), p8, f0);     f1 = pkfma(bc(W4.w), p9, f1);                  \
    h2 g0 = bc(W5.x) * p0,            g1 = bc(W5.y) * p1;                            \
    g0 = pkfma(bc(W5.z), p2, g0);     g1 = pkfma(bc(W5.w), p3, g1);                  \
    g0 = pkfma(bc(W6.x), p4, g0);     g1 = pkfma(bc(W6.y), p5, g1);                  \
    g0 = pkfma(bc(W6.z), p6, g0);     g1 = pkfma(bc(W6.w), p7, g1);                  \
    g0 = pkfma(bc(W7.x), p8, g0);     g1 = pkfma(bc(W7.y), p9, g1);                  \
    h2 o0 = bc(W7.z) * p0,            o1 = bc(W7.w) * p1;                            \
    o0 = pkfma(bc(W8.x), p2, o0);     o1 = pkfma(bc(W8.y), p3, o1);                  \
    o0 = pkfma(bc(W8.z), p4, o0);     o1 = pkfma(bc(W8.w), p5, o1);                  \
    o0 = pkfma(bc(W9.x), p6, o0);     o1 = pkfma(bc(W9.y), p7, o1);                  \
    o0 = pkfma(bc(W9.z), p8, o0);     o1 = pkfma(bc(W9.w), p9, o1);                  \
    float aI = __builtin_amdgcn_fdot2(i0 + i1, ones, 0.f, false);                    \
    float aF = __builtin_amdgcn_fdot2(f0 + f1, ones, 0.f, false);                    \
    float aG = __builtin_amdgcn_fdot2(g0 + g1, ones, 0.f, false);                    \
    float aO = __builtin_amdgcn_fdot2(o0 + o1, ones, 0.f, false);                    \
    float kI = sel1 ? aF : aI, oI = sel1 ? aI : aF;                                  \
    float AIF = kI + dpp_mov<0xB1>(oI);                                              \
    float kG = sel1 ? aO : aG, oG = sel1 ? aG : aO;                                  \
    float BGO = kG + dpp_mov<0xB1>(oG);                                              \
    float k2v = sel2 ? BGO : AIF, o2 = sel2 ? AIF : BGO;                             \
    float S = k2v + dpp_mov<0x4E>(o2);

#define PRODUCE(TP) {                                                                \
    DOTS_REDUCE(&hist[TP][q4 * 24])                                                  \
    xp[(TP) & 3][q4][e] = S + bias;                                                  \
}

        // ---- prologue: producers fill xp for t = 0..LAG-1 ----
        for (int pp = 0; pp < LAG; ++pp) {
            if (isProd) { PRODUCE(pp) }
            __syncthreads();
        }

        // ---- main scan: chain consumes xp[t] while producers build xp[t+LAG] ----
#pragma unroll 2
        for (int t = 0; t < T_; ++t) {
            if (isProd) {
                int tp = t + LAG;
                if (tp < T_) { PRODUCE(tp) }
            } else {
                DOTS_REDUCE(&hs[par][q4][0])
                S += xp[t & 3][q4][e];                     // x-projection + bias

                float y   = __builtin_amdgcn_rcpf(1.f + __builtin_amdgcn_exp2f(mA * S));
                float act = __builtin_fmaf(bA, y, cA0);    // lane's own gate only
                float t2v  = dpp_mov<0x4E>(act);           // i<-g, f<-o
                float prod = act * t2v;                    // i-lane: i*g
                float t3v  = dpp_mov<0xB1>(prod);          // f-lane receives i*g
                float cnew = __builtin_fmaf(act, cold, t3v);
                float th   = __builtin_fmaf(2.f,
                               __builtin_amdgcn_rcpf(1.f + __builtin_amdgcn_exp2f(-2.885390082f * cnew)),
                               -1.f);
                float h = t2v * th;                        // f-lane: o * tanh(c)
                cold = cnew;
                if (q4 == 1) {
                    _Float16 h16 = (_Float16)h;
                    hs[par ^ 1][0][eS] = h16;              // next-step h
                    hist[t][eS] = h16;                     // history (producers consumed row t at step t-2)
                }
            }
            __syncthreads();
            par ^= 1;
        }
        __syncthreads();
#undef PRODUCE
#undef DOTS_REDUCE
    }

    // ---- fc on final hidden state ----
    if (tid < NC_) {
        float acc = fcb[tid];
#pragma unroll
        for (int j = 0; j < H_; ++j)
            acc += fcw[tid * H_ + j] * (float)hist[T_ - 1][(j / 20) * 24 + (j % 20)];
        out[b * NC_ + tid] = acc;
    }
}

extern "C" void kernel_launch(void* const* d_in, const int* in_sizes, int n_in,
                              void* d_out, int out_size, void* d_ws, size_t ws_size,
                              hipStream_t stream) {
    const float* x    = (const float*)d_in[0];
    const float* Wih0 = (const float*)d_in[1];
    const float* WihR = (const float*)d_in[2];
    const float* Whh  = (const float*)d_in[3];
    const float* bih  = (const float*)d_in[4];
    const float* bhh  = (const float*)d_in[5];
    const float* fcw  = (const float*)d_in[6];
    const float* fcb  = (const float*)d_in[7];

    unsigned* w1 = (unsigned*)d_ws;           // 128000 dwords
    unsigned* w2 = w1 + 128000;               // 128000 dwords
    float* bbuf  = (float*)(w2 + 128000);     // 3200 floats

    prep_kernel<<<dim3(500), dim3(256), 0, stream>>>(
        Wih0, WihR, Whh, bih, bhh, w1, w2, bbuf);

    lstm_stack_kernel<<<dim3(B_), dim3(TPB), 0, stream>>>(
        x, (const uint4*)w1, (const uint4*)w2, bbuf, fcw, fcb, (float*)d_out);
}

// Round 18
// 2167.834 us; speedup vs baseline: 1.2401x; 1.2401x over previous
//
#include <hip/hip_runtime.h>

#define B_   256
#define T_   512
#define IN_  34
#define H_   80
#define L_   10
#define NC_  5
#define G4   320
#define TPB  640        // lanes 0-319: group A (even layer), 320-639: group B (odd layer)
#define HPS  96         // row: 2 slices x 48 f16 (40 used + 8 pad)

typedef _Float16 h2 __attribute__((ext_vector_type(2)));

template <int CTRL>
__device__ __forceinline__ float dpp_mov(float v) {
    return __int_as_float(__builtin_amdgcn_update_dpp(0, __float_as_int(v), CTRL, 0xF, 0xF, true));
}
__device__ __forceinline__ h2 bc(unsigned u) { return __builtin_bit_cast(h2, u); }

// Packed weights: uint4 index (l*20 + n)*G4 + lane. lane = e*4 + q4 owns, for all
// 4 gates of rows gate*80+e, the concat-K slice [40*q4, 40*q4+40) of [x(80)|h(80)].
// dword j = n*4+c: gate = j/20, pair q = j%20 -> k = 40*q4 + 2*q. Layer0 x zero-pad.
__global__ void prep_kernel(const float* __restrict__ Wih0, const float* __restrict__ WihR,
                            const float* __restrict__ Whh,  const float* __restrict__ bih,
                            const float* __restrict__ bhh,
                            unsigned* __restrict__ w, float* __restrict__ bbuf) {
    int idx = blockIdx.x * 256 + threadIdx.x;          // dword index
    const int ND = L_ * 20 * G4 * 4;                   // 256000 dwords
    if (idx < ND) {
        int c    = idx & 3;
        int lane = (idx >> 2) % G4;
        int n    = ((idx >> 2) / G4) % 20;
        int l    = (idx >> 2) / (G4 * 20);
        int j = n * 4 + c;
        int gate = j / 20, q = j % 20;
        int e = lane >> 2, q4 = lane & 3;
        int row = gate * H_ + e;
        int kk = 40 * q4 + 2 * q;                      // concat-K of pair start
        float a, bvl;
        if (kk < H_) {                                 // x-side
            if (l == 0) {
                a   = (kk     < IN_) ? Wih0[row * IN_ + kk]     : 0.f;
                bvl = (kk + 1 < IN_) ? Wih0[row * IN_ + kk + 1] : 0.f;
            } else {
                const float* p = WihR + ((size_t)(l - 1) * G4 + row) * H_;
                a = p[kk]; bvl = p[kk + 1];
            }
        } else {                                       // h-side
            const float* p = Whh + ((size_t)l * G4 + row) * H_;
            a = p[kk - H_]; bvl = p[kk - H_ + 1];
        }
        h2 pa; pa[0] = (_Float16)a; pa[1] = (_Float16)bvl;
        w[idx] = __builtin_bit_cast(unsigned, pa);
    }
    if (idx < L_ * G4) bbuf[idx] = bih[idx] + bhh[idx];
}

__global__ __launch_bounds__(TPB, 1) void lstm_stack_kernel(
    const float* __restrict__ x,      // [B,T,34]
    const uint4* __restrict__ w,      // packed f16x2 weights
    const float* __restrict__ bbuf,   // [10][320]
    const float* __restrict__ fcw,    // [5,80]
    const float* __restrict__ fcb,    // [5]
    float* __restrict__ out)          // [B,5]
{
    const int b    = blockIdx.x;
    const int tid  = threadIdx.x;             // 0..639
    const bool isB = tid >= G4;               // group B: odd layer, trails by 1 tick
    const int lane = isB ? tid - G4 : tid;    // 0..319
    const int e    = lane >> 2;               // h element 0..79
    const int q4   = lane & 3;                // K-slice id == final gate id (0=i 1=f 2=g 3=o)
    const int eS   = (e / 40) * 48 + (e % 40);  // sliced column of element e

    const float mA  = (q4 == 2) ? -2.885390082f : -1.442695041f;
    const float bA  = (q4 == 2) ? 2.f : 1.f;
    const float cA0 = (q4 == 2) ? -1.f : 0.f;
    const bool  sel1 = (q4 & 1) != 0;
    const bool  sel2 = (q4 & 2) != 0;

    __shared__ __align__(16) _Float16 hist[T_][HPS];  // 96 KB: x then inter-pass h history
    __shared__ __align__(16) _Float16 xh[2][HPS];     // A->B handoff ring (tick parity)
    __shared__ __align__(16) _Float16 hsA[2][HPS];    // group A h(t-1) ping-pong
    __shared__ __align__(16) _Float16 hsB[2][HPS];    // group B h(t-1) ping-pong

    // ---- stage x -> f16 hist (zero-pad 34..79); slice pads never read ----
    for (int j = tid; j < T_ * H_; j += TPB) {
        int t = j / H_, k = j % H_;
        float v = (k < IN_) ? x[((size_t)b * T_ + t) * IN_ + k] : 0.f;
        hist[t][(k / 40) * 48 + (k % 40)] = (_Float16)v;
    }

    for (int pass = 0; pass < 5; ++pass) {
        const int l = 2 * pass + (isB ? 1 : 0);

        // ---- 20 uint4 weights (80 dwords) — residency is THE experiment ----
        const uint4* wp = w + (size_t)l * 20 * G4 + lane;
        uint4 U0 = wp[0 * G4],  U1 = wp[1 * G4],  U2 = wp[2 * G4],  U3 = wp[3 * G4],  U4 = wp[4 * G4];
        uint4 U5 = wp[5 * G4],  U6 = wp[6 * G4],  U7 = wp[7 * G4],  U8 = wp[8 * G4],  U9 = wp[9 * G4];
        uint4 U10 = wp[10 * G4], U11 = wp[11 * G4], U12 = wp[12 * G4], U13 = wp[13 * G4], U14 = wp[14 * G4];
        uint4 U15 = wp[15 * G4], U16 = wp[16 * G4], U17 = wp[17 * G4], U18 = wp[18 * G4], U19 = wp[19 * G4];
        const float bias = bbuf[l * G4 + q4 * H_ + e];

        // zero both h rings (h(-1) = 0)
        if (tid < 96)               ((unsigned*)hsA)[tid] = 0;
        else if (tid < 192)         ((unsigned*)hsB)[tid - 96] = 0;
        __syncthreads();

        float cold = 0.f;

        for (int tick = 0; tick <= T_; ++tick) {
            const int tau = isB ? tick - 1 : tick;
            if (tau >= 0 && tau < T_) {
                // ---- input slice: q4<2 = x-side (hist row / xh ring), q4>=2 = own h ----
                const int par = tau & 1;
                const uint4* src;
                if (q4 < 2) src = isB ? (const uint4*)(&xh[(tick - 1) & 1][48 * q4])
                                      : (const uint4*)(&hist[tau][48 * q4]);
                else        src = isB ? (const uint4*)(&hsB[par][48 * (q4 - 2)])
                                      : (const uint4*)(&hsA[par][48 * (q4 - 2)]);
                uint4 M0 = src[0], M1 = src[1], M2 = src[2], M3 = src[3], M4 = src[4];
                h2 p0 = bc(M0.x), p1 = bc(M0.y), p2 = bc(M0.z), p3 = bc(M0.w);
                h2 p4 = bc(M1.x), p5 = bc(M1.y), p6 = bc(M1.z), p7 = bc(M1.w);
                h2 p8 = bc(M2.x), p9 = bc(M2.y), p10 = bc(M2.z), p11 = bc(M2.w);
                h2 p12 = bc(M3.x), p13 = bc(M3.y), p14 = bc(M3.z), p15 = bc(M3.w);
                h2 p16 = bc(M4.x), p17 = bc(M4.y), p18 = bc(M4.z), p19 = bc(M4.w);

                float aI = 0.f, aF = 0.f, aG = 0.f, aO = 0.f;
#define D(acc, W, C, P) acc = __builtin_amdgcn_fdot2(bc(W.C), P, acc, false);
                D(aI, U0, x, p0)  D(aI, U0, y, p1)  D(aI, U0, z, p2)  D(aI, U0, w, p3)
                D(aI, U1, x, p4)  D(aI, U1, y, p5)  D(aI, U1, z, p6)  D(aI, U1, w, p7)
                D(aI, U2, x, p8)  D(aI, U2, y, p9)  D(aI, U2, z, p10) D(aI, U2, w, p11)
                D(aI, U3, x, p12) D(aI, U3, y, p13) D(aI, U3, z, p14) D(aI, U3, w, p15)
                D(aI, U4, x, p16) D(aI, U4, y, p17) D(aI, U4, z, p18) D(aI, U4, w, p19)
                D(aF, U5, x, p0)  D(aF, U5, y, p1)  D(aF, U5, z, p2)  D(aF, U5, w, p3)
                D(aF, U6, x, p4)  D(aF, U6, y, p5)  D(aF, U6, z, p6)  D(aF, U6, w, p7)
                D(aF, U7, x, p8)  D(aF, U7, y, p9)  D(aF, U7, z, p10) D(aF, U7, w, p11)
                D(aF, U8, x, p12) D(aF, U8, y, p13) D(aF, U8, z, p14) D(aF, U8, w, p15)
                D(aF, U9, x, p16) D(aF, U9, y, p17) D(aF, U9, z, p18) D(aF, U9, w, p19)
                D(aG, U10, x, p0)  D(aG, U10, y, p1)  D(aG, U10, z, p2)  D(aG, U10, w, p3)
                D(aG, U11, x, p4)  D(aG, U11, y, p5)  D(aG, U11, z, p6)  D(aG, U11, w, p7)
                D(aG, U12, x, p8)  D(aG, U12, y, p9)  D(aG, U12, z, p10) D(aG, U12, w, p11)
                D(aG, U13, x, p12) D(aG, U13, y, p13) D(aG, U13, z, p14) D(aG, U13, w, p15)
                D(aG, U14, x, p16) D(aG, U14, y, p17) D(aG, U14, z, p18) D(aG, U14, w, p19)
                D(aO, U15, x, p0)  D(aO, U15, y, p1)  D(aO, U15, z, p2)  D(aO, U15, w, p3)
                D(aO, U16, x, p4)  D(aO, U16, y, p5)  D(aO, U16, z, p6)  D(aO, U16, w, p7)
                D(aO, U17, x, p8)  D(aO, U17, y, p9)  D(aO, U17, z, p10) D(aO, U17, w, p11)
                D(aO, U18, x, p12) D(aO, U18, y, p13) D(aO, U18, z, p14) D(aO, U18, w, p15)
                D(aO, U19, x, p16) D(aO, U19, y, p17) D(aO, U19, z, p18) D(aO, U19, w, p19)
#undef D
                // ---- distribute-reduce: lane q4 ends with gate q4's 4-slice total ----
                float kI = sel1 ? aF : aI, oI = sel1 ? aI : aF;
                float AIF = kI + dpp_mov<0xB1>(oI);
                float kG = sel1 ? aO : aG, oG = sel1 ? aG : aO;
                float BGO = kG + dpp_mov<0xB1>(oG);
                float k2v = sel2 ? BGO : AIF, o2 = sel2 ? AIF : BGO;
                float S = k2v + dpp_mov<0x4E>(o2) + bias;

                float y   = __builtin_amdgcn_rcpf(1.f + __builtin_amdgcn_exp2f(mA * S));
                float act = __builtin_fmaf(bA, y, cA0);    // lane's own gate only
                float t2v  = dpp_mov<0x4E>(act);           // i<-g, f<-o
                float prod = act * t2v;                    // i-lane: i*g
                float t3v  = dpp_mov<0xB1>(prod);          // f-lane receives i*g
                float cnew = __builtin_fmaf(act, cold, t3v);
                float th   = __builtin_fmaf(2.f,
                               __builtin_amdgcn_rcpf(1.f + __builtin_amdgcn_exp2f(-2.885390082f * cnew)),
                               -1.f);
                float h = t2v * th;                        // f-lane: o * tanh(c)
                cold = cnew;

                if (q4 == 1) {
                    _Float16 h16 = (_Float16)h;
                    if (!isB) {
                        hsA[par ^ 1][eS] = h16;            // own recurrence
                        xh[tick & 1][eS] = h16;            // handoff to B next tick
                    } else {
                        hsB[par ^ 1][eS] = h16;
                        hist[tau][eS] = h16;               // h history for next pass (A consumed hist[tau] last tick)
                    }
                }
            }
            __syncthreads();
        }
    }

    // ---- fc on final hidden state (hist holds h^9 after pass 4) ----
    if (tid < NC_) {
        float acc = fcb[tid];
#pragma unroll
        for (int j = 0; j < H_; ++j)
            acc += fcw[tid * H_ + j] * (float)hist[T_ - 1][(j / 40) * 48 + (j % 40)];
        out[b * NC_ + tid] = acc;
    }
}

extern "C" void kernel_launch(void* const* d_in, const int* in_sizes, int n_in,
                              void* d_out, int out_size, void* d_ws, size_t ws_size,
                              hipStream_t stream) {
    const float* x    = (const float*)d_in[0];
    const float* Wih0 = (const float*)d_in[1];
    const float* WihR = (const float*)d_in[2];
    const float* Whh  = (const float*)d_in[3];
    const float* bih  = (const float*)d_in[4];
    const float* bhh  = (const float*)d_in[5];
    const float* fcw  = (const float*)d_in[6];
    const float* fcb  = (const float*)d_in[7];

    unsigned* w  = (unsigned*)d_ws;           // 256000 dwords
    float* bbuf  = (float*)(w + 256000);      // 3200 floats

    prep_kernel<<<dim3(1000), dim3(256), 0, stream>>>(
        Wih0, WihR, Whh, bih, bhh, w, bbuf);

    lstm_stack_kernel<<<dim3(B_), dim3(TPB), 0, stream>>>(
        x, (const uint4*)w, bbuf, fcw, fcb, (float*)d_out);
}